// Round 3
// baseline (1421.224 us; speedup 1.0000x reference)
//
#include <hip/hip_runtime.h>
#include <math.h>

#define F_IN 128
#define F_HID 16
#define F_OUT 8
#define BSHIFT 7
#define BNODES 128  // nodes per bucket = 1<<BSHIFT

// ---------------- zero bucket counters ----------------

__global__ void k_zero(int* __restrict__ p, int m) {
    int i = blockIdx.x * blockDim.x + threadIdx.x;
    if (i < m) p[i] = 0;
}

// ---------------- bucket histogram (LDS-aggregated) ----------------

__global__ __launch_bounds__(256) void k_hist(const int* __restrict__ dst,
                                              int* __restrict__ bucket_cnt,
                                              int e, int nb) {
    __shared__ int sh[1024];
    int t = threadIdx.x;
    for (int i = t; i < nb; i += 256) sh[i] = 0;
    __syncthreads();
    int stride = gridDim.x * 256;
    for (int i = blockIdx.x * 256 + t; i < e; i += stride)
        atomicAdd(&sh[dst[i] >> BSHIFT], 1);
    __syncthreads();
    for (int i = t; i < nb; i += 256)
        if (sh[i]) atomicAdd(&bucket_cnt[i], sh[i]);
}

// ---------------- exclusive scan of bucket counts (nb <= 1024, 1 block) ----------------

__global__ __launch_bounds__(256) void k_scan(const int* __restrict__ bucket_cnt,
                                              int* __restrict__ base,
                                              int* __restrict__ cursor, int nb, int e) {
    __shared__ int sh[256];
    int t = threadIdx.x;
    int v[4], s = 0;
#pragma unroll
    for (int q = 0; q < 4; ++q) {
        int i = t * 4 + q;
        v[q] = (i < nb) ? bucket_cnt[i] : 0;
        s += v[q];
    }
    sh[t] = s;
    __syncthreads();
    for (int off = 1; off < 256; off <<= 1) {
        int x = (t >= off) ? sh[t - off] : 0;
        __syncthreads();
        sh[t] += x;
        __syncthreads();
    }
    int run = (t > 0) ? sh[t - 1] : 0;
#pragma unroll
    for (int q = 0; q < 4; ++q) {
        int i = t * 4 + q;
        if (i < nb) { base[i] = run; cursor[i] = run; }
        run += v[q];
    }
    if (t == 0) base[nb] = e;
}

// ---------------- scatter edges into buckets (int2 {src,dst}) ----------------
// Only nb (~782) active write frontiers -> cache lines fill fully (write amp ~1x).

__global__ __launch_bounds__(256) void k_bucket(const int* __restrict__ src,
                                                const int* __restrict__ dst,
                                                int* __restrict__ cursor,
                                                int2* __restrict__ ebuf, int e) {
    int i = blockIdx.x * 256 + threadIdx.x;
    if (i < e) {
        int s = src[i], d = dst[i];
        int pos = atomicAdd(&cursor[d >> BSHIFT], 1);
        ebuf[pos] = make_int2(s, d);
    }
}

// ---------------- per-bucket degree count -> dinv (no global atomics) ----------------

__global__ __launch_bounds__(256) void k_degdinv(const int2* __restrict__ ebuf,
                                                 const int* __restrict__ base,
                                                 float* __restrict__ dinv, int n) {
    __shared__ int cnt[BNODES];
    int b = blockIdx.x, t = threadIdx.x;
    if (t < BNODES) cnt[t] = 0;
    __syncthreads();
    int st = base[b], en = base[b + 1];
    for (int i = st + t; i < en; i += 256)
        atomicAdd(&cnt[ebuf[i].y & (BNODES - 1)], 1);
    __syncthreads();
    int node = b * BNODES + t;
    if (t < BNODES && node < n) dinv[node] = rsqrtf((float)cnt[t] + 1.0f);
}

// ---------------- layer 1 GEMM: g1 = dinv * (x @ W1) ----------------

__global__ __launch_bounds__(256) void k_gemm1(const float* __restrict__ x,
                                               const float* __restrict__ W1,
                                               const float* __restrict__ dinv,
                                               float* __restrict__ g1, int n) {
    __shared__ float Ws[F_IN][F_HID];
    __shared__ float xs[16][F_IN + 1];
    int t = threadIdx.x;
    for (int i = t; i < F_IN * F_HID; i += 256) Ws[i / F_HID][i % F_HID] = W1[i];
    int row0 = blockIdx.x * 16;
    for (int i = t; i < 16 * F_IN; i += 256) {
        int r = i >> 7, c = i & 127;
        int gr = row0 + r;
        xs[r][c] = (gr < n) ? x[(long long)gr * F_IN + c] : 0.0f;
    }
    __syncthreads();
    int r = t >> 4, c = t & 15;
    float acc = 0.0f;
#pragma unroll
    for (int k = 0; k < F_IN; ++k) acc = fmaf(xs[r][k], Ws[k][c], acc);
    int gr = row0 + r;
    if (gr < n) g1[gr * F_HID + c] = acc * dinv[gr];
}

// ---------------- layer 1 gather: LDS tile accumulate, fused bias+relu ----------------
// 4 lanes per edge, float4 row reads; tile padded [128][17] vs bank conflicts.

__global__ __launch_bounds__(256) void k_gather1(const int2* __restrict__ ebuf,
                                                 const int* __restrict__ base,
                                                 const float* __restrict__ dinv,
                                                 const float* __restrict__ g1,
                                                 const float* __restrict__ b1,
                                                 float* __restrict__ out1, int n) {
    __shared__ float tile[BNODES][F_HID + 1];
    int b = blockIdx.x, t = threadIdx.x;
    for (int i = t; i < BNODES * (F_HID + 1); i += 256) ((float*)tile)[i] = 0.0f;
    __syncthreads();
    int st = base[b], en = base[b + 1];
    int g = t >> 2, q = t & 3;
    for (int i = st + g; i < en; i += 64) {
        int2 ed = ebuf[i];
        const float4 v = *(const float4*)&g1[(size_t)ed.x * F_HID + q * 4];
        float* tp = &tile[ed.y & (BNODES - 1)][q * 4];
        atomicAdd(tp + 0, v.x);
        atomicAdd(tp + 1, v.y);
        atomicAdd(tp + 2, v.z);
        atomicAdd(tp + 3, v.w);
    }
    __syncthreads();
    int f = t & 15;
#pragma unroll
    for (int p = 0; p < 8; ++p) {
        int r = p * 16 + (t >> 4);
        int node = b * BNODES + r;
        if (node < n) {
            float v = tile[r][f] + g1[(size_t)node * F_HID + f];  // + self-loop
            out1[(size_t)node * F_HID + f] = fmaxf(dinv[node] * v + b1[f], 0.0f);
        }
    }
}

// ---------------- layer 2 GEMM: g2 = dinv * (out1 @ W2) ----------------

__global__ __launch_bounds__(256) void k_gemm2(const float* __restrict__ out1,
                                               const float* __restrict__ W2,
                                               const float* __restrict__ dinv,
                                               float* __restrict__ g2, int n) {
    __shared__ float Ws[F_HID][F_OUT];
    int t = threadIdx.x;
    if (t < F_HID * F_OUT) Ws[t / F_OUT][t % F_OUT] = W2[t];
    __syncthreads();
    int i = blockIdx.x * blockDim.x + t;
    if (i >= n) return;
    const float4* p = (const float4*)(&out1[i * F_HID]);
    float r[F_HID];
#pragma unroll
    for (int q = 0; q < 4; ++q) {
        float4 v = p[q];
        r[q * 4 + 0] = v.x; r[q * 4 + 1] = v.y; r[q * 4 + 2] = v.z; r[q * 4 + 3] = v.w;
    }
    float di = dinv[i];
    float o[F_OUT];
#pragma unroll
    for (int j = 0; j < F_OUT; ++j) {
        float acc = 0.0f;
#pragma unroll
        for (int kk = 0; kk < F_HID; ++kk) acc = fmaf(r[kk], Ws[kk][j], acc);
        o[j] = acc * di;
    }
    float4* q4 = (float4*)(&g2[i * F_OUT]);
    q4[0] = make_float4(o[0], o[1], o[2], o[3]);
    q4[1] = make_float4(o[4], o[5], o[6], o[7]);
}

// ---------------- layer 2 gather: LDS tile + fused bias + log_softmax ----------------

__global__ __launch_bounds__(256) void k_gather2(const int2* __restrict__ ebuf,
                                                 const int* __restrict__ base,
                                                 const float* __restrict__ dinv,
                                                 const float* __restrict__ g2,
                                                 const float* __restrict__ b2,
                                                 float* __restrict__ out, int n) {
    __shared__ float tile[BNODES][F_OUT + 1];
    int b = blockIdx.x, t = threadIdx.x;
    for (int i = t; i < BNODES * (F_OUT + 1); i += 256) ((float*)tile)[i] = 0.0f;
    __syncthreads();
    int st = base[b], en = base[b + 1];
    int g = t >> 1, q = t & 1;
    for (int i = st + g; i < en; i += 128) {
        int2 ed = ebuf[i];
        const float4 v = *(const float4*)&g2[(size_t)ed.x * F_OUT + q * 4];
        float* tp = &tile[ed.y & (BNODES - 1)][q * 4];
        atomicAdd(tp + 0, v.x);
        atomicAdd(tp + 1, v.y);
        atomicAdd(tp + 2, v.z);
        atomicAdd(tp + 3, v.w);
    }
    __syncthreads();
    int f = t & 7;
#pragma unroll
    for (int p = 0; p < 4; ++p) {
        int r = p * 32 + (t >> 3);
        int node = b * BNODES + r;
        if (node < n) {
            float v = dinv[node] * (tile[r][f] + g2[(size_t)node * F_OUT + f]) + b2[f];
            float m = v;
            m = fmaxf(m, __shfl_xor(m, 1));
            m = fmaxf(m, __shfl_xor(m, 2));
            m = fmaxf(m, __shfl_xor(m, 4));
            float ex = expf(v - m);
            float ss = ex;
            ss += __shfl_xor(ss, 1);
            ss += __shfl_xor(ss, 2);
            ss += __shfl_xor(ss, 4);
            out[(size_t)node * F_OUT + f] = v - m - logf(ss);
        }
    }
}

// ---------------- launch ----------------

extern "C" void kernel_launch(void* const* d_in, const int* in_sizes, int n_in,
                              void* d_out, int out_size, void* d_ws, size_t ws_size,
                              hipStream_t stream) {
    const float* x  = (const float*)d_in[0];
    const int*   ei = (const int*)d_in[1];
    const float* W1 = (const float*)d_in[2];
    const float* b1 = (const float*)d_in[3];
    const float* W2 = (const float*)d_in[4];
    const float* b2 = (const float*)d_in[5];
    float* out = (float*)d_out;

    const int n = in_sizes[0] / F_IN;   // 100000
    const int e = in_sizes[1] / 2;      // 3200000
    const int* src = ei;
    const int* dst = ei + e;
    const int nb = (n + BNODES - 1) / BNODES;  // 782

    char* w = (char*)d_ws;
    float* dinv       = (float*)w; w += (size_t)n * 4;        // 16B-aligned sizes
    int2* ebuf        = (int2*)w;  w += (size_t)e * 8;
    int* bucket_cnt   = (int*)w;   w += (size_t)(nb + 4) * 4;
    int* base         = (int*)w;   w += (size_t)(nb + 4) * 4;
    int* cursor       = (int*)w;   w += (size_t)(nb + 4) * 4;
    w = (char*)(((size_t)w + 15) & ~(size_t)15);
    float* g1         = (float*)w; w += (size_t)n * F_HID * 4;
    float* out1       = (float*)w; w += (size_t)n * F_HID * 4;
    float* g2         = (float*)w; w += (size_t)n * F_OUT * 4;

    k_zero<<<(nb + 255) / 256, 256, 0, stream>>>(bucket_cnt, nb);
    k_hist<<<196, 256, 0, stream>>>(dst, bucket_cnt, e, nb);
    k_scan<<<1, 256, 0, stream>>>(bucket_cnt, base, cursor, nb, e);
    k_bucket<<<(e + 255) / 256, 256, 0, stream>>>(src, dst, cursor, ebuf, e);
    k_degdinv<<<nb, 256, 0, stream>>>(ebuf, base, dinv, n);
    k_gemm1<<<(n + 15) / 16, 256, 0, stream>>>(x, W1, dinv, g1, n);
    k_gather1<<<nb, 256, 0, stream>>>(ebuf, base, dinv, g1, b1, out1, n);
    k_gemm2<<<(n + 255) / 256, 256, 0, stream>>>(out1, W2, dinv, g2, n);
    k_gather2<<<nb, 256, 0, stream>>>(ebuf, base, dinv, g2, b2, out, n);
}

// Round 4
// 732.727 us; speedup vs baseline: 1.9396x; 1.9396x over previous
//
#include <hip/hip_runtime.h>
#include <math.h>

#define F_IN 128
#define F_HID 16
#define F_OUT 8
#define BSHIFT 8
#define BNODES 256   // nodes per bucket = 1<<BSHIFT
#define MAXNB 512    // LDS arrays sized for nb <= 512
#define CHUNK 16384  // edges per block in k_bucket

// ---------------- zero bucket counters ----------------

__global__ void k_zero(int* __restrict__ p, int m) {
    int i = blockIdx.x * blockDim.x + threadIdx.x;
    if (i < m) p[i] = 0;
}

// ---------------- bucket histogram (LDS-aggregated) ----------------

__global__ __launch_bounds__(256) void k_hist(const int* __restrict__ dst,
                                              int* __restrict__ bucket_cnt,
                                              int e, int nb) {
    __shared__ int sh[MAXNB];
    int t = threadIdx.x;
    for (int i = t; i < nb; i += 256) sh[i] = 0;
    __syncthreads();
    int stride = gridDim.x * 256;
    for (int i = blockIdx.x * 256 + t; i < e; i += stride)
        atomicAdd(&sh[dst[i] >> BSHIFT], 1);
    __syncthreads();
    for (int i = t; i < nb; i += 256)
        if (sh[i]) atomicAdd(&bucket_cnt[i], sh[i]);
}

// ---------------- exclusive scan of bucket counts (nb <= 1024, 1 block) ----------------

__global__ __launch_bounds__(256) void k_scan(const int* __restrict__ bucket_cnt,
                                              int* __restrict__ base,
                                              int* __restrict__ cursor, int nb, int e) {
    __shared__ int sh[256];
    int t = threadIdx.x;
    int v[4], s = 0;
#pragma unroll
    for (int q = 0; q < 4; ++q) {
        int i = t * 4 + q;
        v[q] = (i < nb) ? bucket_cnt[i] : 0;
        s += v[q];
    }
    sh[t] = s;
    __syncthreads();
    for (int off = 1; off < 256; off <<= 1) {
        int x = (t >= off) ? sh[t - off] : 0;
        __syncthreads();
        sh[t] += x;
        __syncthreads();
    }
    int run = (t > 0) ? sh[t - 1] : 0;
#pragma unroll
    for (int q = 0; q < 4; ++q) {
        int i = t * 4 + q;
        if (i < nb) { base[i] = run; cursor[i] = run; }
        run += v[q];
    }
    if (t == 0) base[nb] = e;
}

// ---------------- rank-then-write bucket scatter ----------------
// Per 16K-edge chunk: LDS hist -> one global atomicAdd per (block,bucket) to
// reserve a contiguous range -> scatter via LDS cursors. Global atomics
// 3.2M -> ~77K; per-(block,bucket) writes are contiguous ~340B runs.

__global__ __launch_bounds__(256) void k_bucket(const int* __restrict__ src,
                                                const int* __restrict__ dst,
                                                int* __restrict__ cursor,
                                                int2* __restrict__ ebuf, int e, int nb) {
    __shared__ int hist[MAXNB];
    __shared__ int ofs[MAXNB];
    int t = threadIdx.x;
    int beg = blockIdx.x * CHUNK;
    int end = min(beg + CHUNK, e);
    for (int i = t; i < nb; i += 256) hist[i] = 0;
    __syncthreads();
    for (int i = beg + t; i < end; i += 256)
        atomicAdd(&hist[dst[i] >> BSHIFT], 1);
    __syncthreads();
    for (int i = t; i < nb; i += 256)
        ofs[i] = hist[i] ? atomicAdd(&cursor[i], hist[i]) : 0;
    __syncthreads();
    for (int i = beg + t; i < end; i += 256) {
        int s = src[i], d = dst[i];
        int pos = atomicAdd(&ofs[d >> BSHIFT], 1);
        ebuf[pos] = make_int2(s, d);
    }
}

// ---------------- per-bucket degree count -> dinv (no global atomics) ----------------

__global__ __launch_bounds__(256) void k_degdinv(const int2* __restrict__ ebuf,
                                                 const int* __restrict__ base,
                                                 float* __restrict__ dinv, int n) {
    __shared__ int cnt[BNODES];
    int b = blockIdx.x, t = threadIdx.x;
    if (t < BNODES) cnt[t] = 0;
    __syncthreads();
    int st = base[b], en = base[b + 1];
    for (int i = st + t; i < en; i += 256)
        atomicAdd(&cnt[ebuf[i].y & (BNODES - 1)], 1);
    __syncthreads();
    int node = b * BNODES + t;
    if (t < BNODES && node < n) dinv[node] = rsqrtf((float)cnt[t] + 1.0f);
}

// ---------------- layer 1 GEMM: g1 = dinv * (x @ W1) ----------------

__global__ __launch_bounds__(256) void k_gemm1(const float* __restrict__ x,
                                               const float* __restrict__ W1,
                                               const float* __restrict__ dinv,
                                               float* __restrict__ g1, int n) {
    __shared__ float Ws[F_IN][F_HID];
    __shared__ float xs[16][F_IN + 1];
    int t = threadIdx.x;
    for (int i = t; i < F_IN * F_HID; i += 256) Ws[i / F_HID][i % F_HID] = W1[i];
    int row0 = blockIdx.x * 16;
    for (int i = t; i < 16 * F_IN; i += 256) {
        int r = i >> 7, c = i & 127;
        int gr = row0 + r;
        xs[r][c] = (gr < n) ? x[(long long)gr * F_IN + c] : 0.0f;
    }
    __syncthreads();
    int r = t >> 4, c = t & 15;
    float acc = 0.0f;
#pragma unroll
    for (int k = 0; k < F_IN; ++k) acc = fmaf(xs[r][k], Ws[k][c], acc);
    int gr = row0 + r;
    if (gr < n) g1[gr * F_HID + c] = acc * dinv[gr];
}

// ---------------- layer 1 gather: LDS tile accumulate, fused bias+relu ----------------
// 4 lanes per edge, float4 row reads; tile padded [256][17] vs bank conflicts.

__global__ __launch_bounds__(256) void k_gather1(const int2* __restrict__ ebuf,
                                                 const int* __restrict__ base,
                                                 const float* __restrict__ dinv,
                                                 const float* __restrict__ g1,
                                                 const float* __restrict__ b1,
                                                 float* __restrict__ out1, int n) {
    __shared__ float tile[BNODES][F_HID + 1];
    int b = blockIdx.x, t = threadIdx.x;
    for (int i = t; i < BNODES * (F_HID + 1); i += 256) ((float*)tile)[i] = 0.0f;
    __syncthreads();
    int st = base[b], en = base[b + 1];
    int g = t >> 2, q = t & 3;
    for (int i = st + g; i < en; i += 64) {
        int2 ed = ebuf[i];
        const float4 v = *(const float4*)&g1[(size_t)ed.x * F_HID + q * 4];
        float* tp = &tile[ed.y & (BNODES - 1)][q * 4];
        atomicAdd(tp + 0, v.x);
        atomicAdd(tp + 1, v.y);
        atomicAdd(tp + 2, v.z);
        atomicAdd(tp + 3, v.w);
    }
    __syncthreads();
    int f = t & 15;
#pragma unroll
    for (int p = 0; p < 16; ++p) {
        int r = p * 16 + (t >> 4);
        int node = b * BNODES + r;
        if (node < n) {
            float v = tile[r][f] + g1[(size_t)node * F_HID + f];  // + self-loop
            out1[(size_t)node * F_HID + f] = fmaxf(dinv[node] * v + b1[f], 0.0f);
        }
    }
}

// ---------------- layer 2 GEMM: g2 = dinv * (out1 @ W2) ----------------

__global__ __launch_bounds__(256) void k_gemm2(const float* __restrict__ out1,
                                               const float* __restrict__ W2,
                                               const float* __restrict__ dinv,
                                               float* __restrict__ g2, int n) {
    __shared__ float Ws[F_HID][F_OUT];
    int t = threadIdx.x;
    if (t < F_HID * F_OUT) Ws[t / F_OUT][t % F_OUT] = W2[t];
    __syncthreads();
    int i = blockIdx.x * blockDim.x + t;
    if (i >= n) return;
    const float4* p = (const float4*)(&out1[i * F_HID]);
    float r[F_HID];
#pragma unroll
    for (int q = 0; q < 4; ++q) {
        float4 v = p[q];
        r[q * 4 + 0] = v.x; r[q * 4 + 1] = v.y; r[q * 4 + 2] = v.z; r[q * 4 + 3] = v.w;
    }
    float di = dinv[i];
    float o[F_OUT];
#pragma unroll
    for (int j = 0; j < F_OUT; ++j) {
        float acc = 0.0f;
#pragma unroll
        for (int kk = 0; kk < F_HID; ++kk) acc = fmaf(r[kk], Ws[kk][j], acc);
        o[j] = acc * di;
    }
    float4* q4 = (float4*)(&g2[i * F_OUT]);
    q4[0] = make_float4(o[0], o[1], o[2], o[3]);
    q4[1] = make_float4(o[4], o[5], o[6], o[7]);
}

// ---------------- layer 2 gather: LDS tile + fused bias + log_softmax ----------------

__global__ __launch_bounds__(256) void k_gather2(const int2* __restrict__ ebuf,
                                                 const int* __restrict__ base,
                                                 const float* __restrict__ dinv,
                                                 const float* __restrict__ g2,
                                                 const float* __restrict__ b2,
                                                 float* __restrict__ out, int n) {
    __shared__ float tile[BNODES][F_OUT + 1];
    int b = blockIdx.x, t = threadIdx.x;
    for (int i = t; i < BNODES * (F_OUT + 1); i += 256) ((float*)tile)[i] = 0.0f;
    __syncthreads();
    int st = base[b], en = base[b + 1];
    int g = t >> 1, q = t & 1;
    for (int i = st + g; i < en; i += 128) {
        int2 ed = ebuf[i];
        const float4 v = *(const float4*)&g2[(size_t)ed.x * F_OUT + q * 4];
        float* tp = &tile[ed.y & (BNODES - 1)][q * 4];
        atomicAdd(tp + 0, v.x);
        atomicAdd(tp + 1, v.y);
        atomicAdd(tp + 2, v.z);
        atomicAdd(tp + 3, v.w);
    }
    __syncthreads();
    int f = t & 7;
#pragma unroll
    for (int p = 0; p < 8; ++p) {
        int r = p * 32 + (t >> 3);
        int node = b * BNODES + r;
        if (node < n) {
            float v = dinv[node] * (tile[r][f] + g2[(size_t)node * F_OUT + f]) + b2[f];
            float m = v;
            m = fmaxf(m, __shfl_xor(m, 1));
            m = fmaxf(m, __shfl_xor(m, 2));
            m = fmaxf(m, __shfl_xor(m, 4));
            float ex = expf(v - m);
            float ss = ex;
            ss += __shfl_xor(ss, 1);
            ss += __shfl_xor(ss, 2);
            ss += __shfl_xor(ss, 4);
            out[(size_t)node * F_OUT + f] = v - m - logf(ss);
        }
    }
}

// ---------------- launch ----------------

extern "C" void kernel_launch(void* const* d_in, const int* in_sizes, int n_in,
                              void* d_out, int out_size, void* d_ws, size_t ws_size,
                              hipStream_t stream) {
    const float* x  = (const float*)d_in[0];
    const int*   ei = (const int*)d_in[1];
    const float* W1 = (const float*)d_in[2];
    const float* b1 = (const float*)d_in[3];
    const float* W2 = (const float*)d_in[4];
    const float* b2 = (const float*)d_in[5];
    float* out = (float*)d_out;

    const int n = in_sizes[0] / F_IN;   // 100000
    const int e = in_sizes[1] / 2;      // 3200000
    const int* src = ei;
    const int* dst = ei + e;
    const int nb = (n + BNODES - 1) / BNODES;  // 391

    char* w = (char*)d_ws;
    float* dinv       = (float*)w; w += (size_t)n * 4;
    int2* ebuf        = (int2*)w;  w += (size_t)e * 8;
    int* bucket_cnt   = (int*)w;   w += (size_t)(nb + 4) * 4;
    int* base         = (int*)w;   w += (size_t)(nb + 4) * 4;
    int* cursor       = (int*)w;   w += (size_t)(nb + 4) * 4;
    w = (char*)(((size_t)w + 15) & ~(size_t)15);
    float* g1         = (float*)w; w += (size_t)n * F_HID * 4;
    float* out1       = (float*)w; w += (size_t)n * F_HID * 4;
    float* g2         = (float*)w; w += (size_t)n * F_OUT * 4;

    k_zero<<<(nb + 255) / 256, 256, 0, stream>>>(bucket_cnt, nb);
    k_hist<<<256, 256, 0, stream>>>(dst, bucket_cnt, e, nb);
    k_scan<<<1, 256, 0, stream>>>(bucket_cnt, base, cursor, nb, e);
    k_bucket<<<(e + CHUNK - 1) / CHUNK, 256, 0, stream>>>(src, dst, cursor, ebuf, e, nb);
    k_degdinv<<<nb, 256, 0, stream>>>(ebuf, base, dinv, n);
    k_gemm1<<<(n + 15) / 16, 256, 0, stream>>>(x, W1, dinv, g1, n);
    k_gather1<<<nb, 256, 0, stream>>>(ebuf, base, dinv, g1, b1, out1, n);
    k_gemm2<<<(n + 255) / 256, 256, 0, stream>>>(out1, W2, dinv, g2, n);
    k_gather2<<<nb, 256, 0, stream>>>(ebuf, base, dinv, g2, b2, out, n);
}

// Round 6
// 710.931 us; speedup vs baseline: 1.9991x; 1.0307x over previous
//
#include <hip/hip_runtime.h>
#include <math.h>

#define F_IN 128
#define F_HID 16
#define F_OUT 8
#define BSHIFT 7
#define BNODES 128   // nodes per bucket = 1<<BSHIFT
#define MAXNB 1024   // LDS arrays sized for nb <= 1024 (nb = 782)
#define CHUNK 8192   // edges per block in k_bucket

// ---------------- zero bucket counters ----------------

__global__ void k_zero(int* __restrict__ p, int m) {
    int i = blockIdx.x * blockDim.x + threadIdx.x;
    if (i < m) p[i] = 0;
}

// ---------------- bucket histogram (LDS-aggregated) ----------------

__global__ __launch_bounds__(256) void k_hist(const int* __restrict__ dst,
                                              int* __restrict__ bucket_cnt,
                                              int e, int nb) {
    __shared__ int sh[MAXNB];
    int t = threadIdx.x;
    for (int i = t; i < nb; i += 256) sh[i] = 0;
    __syncthreads();
    int stride = gridDim.x * 256;
    for (int i = blockIdx.x * 256 + t; i < e; i += stride)
        atomicAdd(&sh[dst[i] >> BSHIFT], 1);
    __syncthreads();
    for (int i = t; i < nb; i += 256)
        if (sh[i]) atomicAdd(&bucket_cnt[i], sh[i]);
}

// ---------------- exclusive scan of bucket counts (nb <= 1024, 1 block) ----------------

__global__ __launch_bounds__(256) void k_scan(const int* __restrict__ bucket_cnt,
                                              int* __restrict__ base,
                                              int* __restrict__ cursor, int nb, int e) {
    __shared__ int sh[256];
    int t = threadIdx.x;
    int v[4], s = 0;
#pragma unroll
    for (int q = 0; q < 4; ++q) {
        int i = t * 4 + q;
        v[q] = (i < nb) ? bucket_cnt[i] : 0;
        s += v[q];
    }
    sh[t] = s;
    __syncthreads();
    for (int off = 1; off < 256; off <<= 1) {
        int x = (t >= off) ? sh[t - off] : 0;
        __syncthreads();
        sh[t] += x;
        __syncthreads();
    }
    int run = (t > 0) ? sh[t - 1] : 0;
#pragma unroll
    for (int q = 0; q < 4; ++q) {
        int i = t * 4 + q;
        if (i < nb) { base[i] = run; cursor[i] = run; }
        run += v[q];
    }
    if (t == 0) base[nb] = e;
}

// ---------------- rank-then-write bucket scatter (packed 4B edges) ----------------
// Per 8K-edge chunk: LDS hist -> one global atomicAdd per (block,bucket) to
// reserve a contiguous range -> scatter via LDS cursors.

__global__ __launch_bounds__(1024) void k_bucket(const int* __restrict__ src,
                                                 const int* __restrict__ dst,
                                                 int* __restrict__ cursor,
                                                 int* __restrict__ ebuf, int e, int nb) {
    __shared__ int hist[MAXNB];
    __shared__ int ofs[MAXNB];
    int t = threadIdx.x;
    int beg = blockIdx.x * CHUNK;
    int end = min(beg + CHUNK, e);
    for (int i = t; i < nb; i += 1024) hist[i] = 0;
    __syncthreads();
    for (int i = beg + t; i < end; i += 1024)
        atomicAdd(&hist[dst[i] >> BSHIFT], 1);
    __syncthreads();
    for (int i = t; i < nb; i += 1024)
        ofs[i] = hist[i] ? atomicAdd(&cursor[i], hist[i]) : 0;
    __syncthreads();
    for (int i = beg + t; i < end; i += 1024) {
        int s = src[i], d = dst[i];
        int pos = atomicAdd(&ofs[d >> BSHIFT], 1);
        ebuf[pos] = (s << BSHIFT) | (d & (BNODES - 1));
    }
}

// ---------------- per-bucket degree count -> dinv (no global atomics) ----------------

__global__ __launch_bounds__(256) void k_degdinv(const int* __restrict__ ebuf,
                                                 const int* __restrict__ base,
                                                 float* __restrict__ dinv, int n) {
    __shared__ int cnt[BNODES];
    int b = blockIdx.x, t = threadIdx.x;
    if (t < BNODES) cnt[t] = 0;
    __syncthreads();
    int st = base[b], en = base[b + 1];
    for (int i = st + t; i < en; i += 256)
        atomicAdd(&cnt[ebuf[i] & (BNODES - 1)], 1);
    __syncthreads();
    int node = b * BNODES + t;
    if (t < BNODES && node < n) dinv[node] = rsqrtf((float)cnt[t] + 1.0f);
}

// ---------------- layer 1 GEMM: g1 = dinv * (x @ W1) ----------------

__global__ __launch_bounds__(256) void k_gemm1(const float* __restrict__ x,
                                               const float* __restrict__ W1,
                                               const float* __restrict__ dinv,
                                               float* __restrict__ g1, int n) {
    __shared__ float Ws[F_IN][F_HID];
    __shared__ float xs[16][F_IN + 1];
    int t = threadIdx.x;
    for (int i = t; i < F_IN * F_HID; i += 256) Ws[i / F_HID][i % F_HID] = W1[i];
    int row0 = blockIdx.x * 16;
    for (int i = t; i < 16 * F_IN; i += 256) {
        int r = i >> 7, c = i & 127;
        int gr = row0 + r;
        xs[r][c] = (gr < n) ? x[(long long)gr * F_IN + c] : 0.0f;
    }
    __syncthreads();
    int r = t >> 4, c = t & 15;
    float acc = 0.0f;
#pragma unroll
    for (int k = 0; k < F_IN; ++k) acc = fmaf(xs[r][k], Ws[k][c], acc);
    int gr = row0 + r;
    if (gr < n) g1[gr * F_HID + c] = acc * dinv[gr];
}

// ---------------- layer 1 gather: LDS tile accumulate, fused bias+relu ----------------
// 1024 threads, 4 lanes per edge; packed-edge prefetch pipeline.

__global__ __launch_bounds__(1024) void k_gather1(const int* __restrict__ ebuf,
                                                  const int* __restrict__ base,
                                                  const float* __restrict__ dinv,
                                                  const float* __restrict__ g1,
                                                  const float* __restrict__ b1,
                                                  float* __restrict__ out1, int n) {
    __shared__ float tile[BNODES][F_HID + 1];
    int b = blockIdx.x, t = threadIdx.x;
    for (int i = t; i < BNODES * (F_HID + 1); i += 1024) ((float*)tile)[i] = 0.0f;
    __syncthreads();
    int st = base[b], en = base[b + 1];
    int g = t >> 2, q = t & 3;
    int i = st + g;
    int ep = (i < en) ? ebuf[i] : 0;
    while (i < en) {
        int inext = i + 256;
        int epn = (inext < en) ? ebuf[inext] : 0;
        int s = ep >> BSHIFT, r = ep & (BNODES - 1);
        const float4 v = *(const float4*)&g1[(size_t)s * F_HID + q * 4];
        float* tp = &tile[r][q * 4];
        atomicAdd(tp + 0, v.x);
        atomicAdd(tp + 1, v.y);
        atomicAdd(tp + 2, v.z);
        atomicAdd(tp + 3, v.w);
        ep = epn;
        i = inext;
    }
    __syncthreads();
    int f = t & 15;
#pragma unroll
    for (int p = 0; p < 2; ++p) {
        int r = p * 64 + (t >> 4);
        int node = b * BNODES + r;
        if (node < n) {
            float v = tile[r][f] + g1[(size_t)node * F_HID + f];  // + self-loop
            out1[(size_t)node * F_HID + f] = fmaxf(dinv[node] * v + b1[f], 0.0f);
        }
    }
}

// ---------------- layer 2 GEMM: g2 = dinv * (out1 @ W2) ----------------

__global__ __launch_bounds__(256) void k_gemm2(const float* __restrict__ out1,
                                               const float* __restrict__ W2,
                                               const float* __restrict__ dinv,
                                               float* __restrict__ g2, int n) {
    __shared__ float Ws[F_HID][F_OUT];
    int t = threadIdx.x;
    if (t < F_HID * F_OUT) Ws[t / F_OUT][t % F_OUT] = W2[t];
    __syncthreads();
    int i = blockIdx.x * blockDim.x + t;
    if (i >= n) return;
    const float4* p = (const float4*)(&out1[i * F_HID]);
    float r[F_HID];
#pragma unroll
    for (int q = 0; q < 4; ++q) {
        float4 v = p[q];
        r[q * 4 + 0] = v.x; r[q * 4 + 1] = v.y; r[q * 4 + 2] = v.z; r[q * 4 + 3] = v.w;
    }
    float di = dinv[i];
    float o[F_OUT];
#pragma unroll
    for (int j = 0; j < F_OUT; ++j) {
        float acc = 0.0f;
#pragma unroll
        for (int kk = 0; kk < F_HID; ++kk) acc = fmaf(r[kk], Ws[kk][j], acc);
        o[j] = acc * di;
    }
    float4* q4 = (float4*)(&g2[i * F_OUT]);
    q4[0] = make_float4(o[0], o[1], o[2], o[3]);
    q4[1] = make_float4(o[4], o[5], o[6], o[7]);
}

// ---------------- layer 2 gather: LDS tile + fused bias + log_softmax ----------------
// 1024 threads, 2 lanes per edge.

__global__ __launch_bounds__(1024) void k_gather2(const int* __restrict__ ebuf,
                                                  const int* __restrict__ base,
                                                  const float* __restrict__ dinv,
                                                  const float* __restrict__ g2,
                                                  const float* __restrict__ b2,
                                                  float* __restrict__ out, int n) {
    __shared__ float tile[BNODES][F_OUT + 1];
    int b = blockIdx.x, t = threadIdx.x;
    for (int i = t; i < BNODES * (F_OUT + 1); i += 1024) ((float*)tile)[i] = 0.0f;
    __syncthreads();
    int st = base[b], en = base[b + 1];
    int g = t >> 1, q = t & 1;
    int i = st + g;
    int ep = (i < en) ? ebuf[i] : 0;
    while (i < en) {
        int inext = i + 512;
        int epn = (inext < en) ? ebuf[inext] : 0;
        int s = ep >> BSHIFT, r = ep & (BNODES - 1);
        const float4 v = *(const float4*)&g2[(size_t)s * F_OUT + q * 4];
        float* tp = &tile[r][q * 4];
        atomicAdd(tp + 0, v.x);
        atomicAdd(tp + 1, v.y);
        atomicAdd(tp + 2, v.z);
        atomicAdd(tp + 3, v.w);
        ep = epn;
        i = inext;
    }
    __syncthreads();
    int f = t & 7;
    int r = t >> 3;  // 0..127, exactly one pass
    int node = b * BNODES + r;
    if (node < n) {
        float v = dinv[node] * (tile[r][f] + g2[(size_t)node * F_OUT + f]) + b2[f];
        float m = v;
        m = fmaxf(m, __shfl_xor(m, 1));
        m = fmaxf(m, __shfl_xor(m, 2));
        m = fmaxf(m, __shfl_xor(m, 4));
        float ex = expf(v - m);
        float ss = ex;
        ss += __shfl_xor(ss, 1);
        ss += __shfl_xor(ss, 2);
        ss += __shfl_xor(ss, 4);
        out[(size_t)node * F_OUT + f] = v - m - logf(ss);
    }
}

// ---------------- launch ----------------

extern "C" void kernel_launch(void* const* d_in, const int* in_sizes, int n_in,
                              void* d_out, int out_size, void* d_ws, size_t ws_size,
                              hipStream_t stream) {
    const float* x  = (const float*)d_in[0];
    const int*   ei = (const int*)d_in[1];
    const float* W1 = (const float*)d_in[2];
    const float* b1 = (const float*)d_in[3];
    const float* W2 = (const float*)d_in[4];
    const float* b2 = (const float*)d_in[5];
    float* out = (float*)d_out;

    const int n = in_sizes[0] / F_IN;   // 100000
    const int e = in_sizes[1] / 2;      // 3200000
    const int* src = ei;
    const int* dst = ei + e;
    const int nb = (n + BNODES - 1) / BNODES;  // 782

    char* w = (char*)d_ws;
    float* dinv       = (float*)w; w += (size_t)n * 4;
    int* ebuf         = (int*)w;   w += (size_t)e * 4;
    int* bucket_cnt   = (int*)w;   w += (size_t)(nb + 4) * 4;
    int* base         = (int*)w;   w += (size_t)(nb + 4) * 4;
    int* cursor       = (int*)w;   w += (size_t)(nb + 4) * 4;
    w = (char*)(((size_t)w + 15) & ~(size_t)15);
    float* g1         = (float*)w; w += (size_t)n * F_HID * 4;
    float* out1       = (float*)w; w += (size_t)n * F_HID * 4;
    float* g2         = (float*)w; w += (size_t)n * F_OUT * 4;

    k_zero<<<(nb + 255) / 256, 256, 0, stream>>>(bucket_cnt, nb);
    k_hist<<<256, 256, 0, stream>>>(dst, bucket_cnt, e, nb);
    k_scan<<<1, 256, 0, stream>>>(bucket_cnt, base, cursor, nb, e);
    k_bucket<<<(e + CHUNK - 1) / CHUNK, 1024, 0, stream>>>(src, dst, cursor, ebuf, e, nb);
    k_degdinv<<<nb, 256, 0, stream>>>(ebuf, base, dinv, n);
    k_gemm1<<<(n + 15) / 16, 256, 0, stream>>>(x, W1, dinv, g1, n);
    k_gather1<<<nb, 1024, 0, stream>>>(ebuf, base, dinv, g1, b1, out1, n);
    k_gemm2<<<(n + 255) / 256, 256, 0, stream>>>(out1, W2, dinv, g2, n);
    k_gather2<<<nb, 1024, 0, stream>>>(ebuf, base, dinv, g2, b2, out, n);
}